// Round 4
// baseline (127.719 us; speedup 1.0000x reference)
//
#include <hip/hip_runtime.h>

#define NB 64      // L*B batches
#define T 1024     // t1 == t2
#define HD 128     // h

// encoded +inf for order-preserving float-as-uint atomicMin
#define EINF 0xFF800000u

typedef __attribute__((ext_vector_type(8))) short bf16x8;
typedef __attribute__((ext_vector_type(4))) float f32x4;

static __device__ __forceinline__ short f2bf(float f) {
    unsigned u = __float_as_uint(f);
    u += 0x7FFFu + ((u >> 16) & 1u);
    return (short)(u >> 16);
}
static __device__ __forceinline__ unsigned fenc(float f) {
    unsigned b = __float_as_uint(f);
    return b ^ (unsigned)(((int)b >> 31) | (int)0x80000000);
}
static __device__ __forceinline__ float fdec(unsigned u) {
    unsigned m = (~(unsigned)((int)u >> 31)) | 0x80000000u;
    return __uint_as_float(u ^ m);
}

// Phase 0: x,y fp32 -> bf16 + per-row norms + all workspace init. Pure BW.
__global__ void wmd_prep(const float* __restrict__ x, const float* __restrict__ y,
                         short* __restrict__ xbf, short* __restrict__ ybf,
                         float* __restrict__ x2, float* __restrict__ y2,
                         unsigned* __restrict__ g_colmin, unsigned* __restrict__ g_rowmin,
                         float* __restrict__ sums, unsigned* __restrict__ counter) {
    int gi = blockIdx.x * 256 + threadIdx.x;          // float4 index, 2.097M total
    float4 vx = reinterpret_cast<const float4*>(x)[gi];
    float4 vy = reinterpret_cast<const float4*>(y)[gi];
    short4 sx, sy;
    sx.x = f2bf(vx.x); sx.y = f2bf(vx.y); sx.z = f2bf(vx.z); sx.w = f2bf(vx.w);
    sy.x = f2bf(vy.x); sy.y = f2bf(vy.y); sy.z = f2bf(vy.z); sy.w = f2bf(vy.w);
    reinterpret_cast<short4*>(xbf)[gi] = sx;
    reinterpret_cast<short4*>(ybf)[gi] = sy;
    float px = vx.x * vx.x + vx.y * vx.y + vx.z * vx.z + vx.w * vx.w;
    float py = vy.x * vy.x + vy.y * vy.y + vy.z * vy.z + vy.w * vy.w;
    px += __shfl_xor(px, 1);  px += __shfl_xor(px, 2);  px += __shfl_xor(px, 4);
    px += __shfl_xor(px, 8);  px += __shfl_xor(px, 16);
    py += __shfl_xor(py, 1);  py += __shfl_xor(py, 2);  py += __shfl_xor(py, 4);
    py += __shfl_xor(py, 8);  py += __shfl_xor(py, 16);
    if ((threadIdx.x & 31) == 0) { x2[gi >> 5] = px; y2[gi >> 5] = py; }
    if (gi < NB * T) { g_colmin[gi] = EINF; g_rowmin[gi] = EINF; }
    if (gi < 2) sums[gi] = 0.f;
    if (gi == 2) counter[0] = 0u;
}

// Phase 1: fused bf16-MFMA GEMM + min tracking.
// 1024 blocks, 256 threads; per wave 32i x 64j. B tiles (64x128) DMA'd via
// global_load_lds (16B, XOR-swizzled), double-buffered. A frags direct from xbf.
// Block swizzle: the 8 i-blocks of one (n, j-half) group share lin&7 -> same XCD.
__global__ __launch_bounds__(256, 4)
void wmd_main(const short* __restrict__ xbf, const short* __restrict__ ybf,
              const float* __restrict__ x2g, const float* __restrict__ y2g,
              unsigned* __restrict__ g_colmin, unsigned* __restrict__ g_rowmin) {
    __shared__ short b_sm[2][64 * 128];        // 2 x 16 KB
    __shared__ float y2_sm[512];
    __shared__ unsigned col_min_sm[512];

    const int tid  = threadIdx.x;
    const int lin  = blockIdx.y * 16 + blockIdx.x;   // 0..1023
    const int m    = (lin >> 3) & 7;                 // i-tile 0..7
    const int grp  = ((lin >> 6) << 3) | (lin & 7);  // 0..127: (n, j-half) group
    const int n    = grp >> 1;
    const int i0   = m * 128;
    const int j0   = (grp & 1) * 512;
    const int lane = tid & 63;
    const int wave = tid >> 6;
    const int l16  = lane & 15, quad = lane >> 4;
    const float FINF = __uint_as_float(0x7F800000u);

    #pragma unroll
    for (int e = tid; e < 512; e += 256) col_min_sm[e] = EINF;

#define ISSUE_GLLS(pbuf, jtile)                                                   \
    {                                                                             \
        const short* ybase = ybf + (((size_t)(n * T + j0 + (jtile) * 64)) << 7);  \
        _Pragma("unroll")                                                         \
        for (int it = 0; it < 4; ++it) {                                          \
            int g   = wave * 4 + it;                                              \
            int s   = g * 64 + lane;                                              \
            int row = s >> 4;                                                     \
            int c   = (s & 15) ^ (row & 7);                                       \
            const short* gp = ybase + row * 128 + c * 8;                          \
            __builtin_amdgcn_global_load_lds(                                     \
                (const __attribute__((address_space(1))) void*)gp,                \
                (__attribute__((address_space(3))) void*)&b_sm[pbuf][g * 512],    \
                16, 0, 0);                                                        \
        }                                                                         \
    }

    ISSUE_GLLS(0, 0);   // tile-0 DMA overlaps prologue

    // ---- A fragments: straight bf16 global -> regs; norms from global ----
    bf16x8 af[2][4];
    #pragma unroll
    for (int mi = 0; mi < 2; ++mi)
        #pragma unroll
        for (int kk = 0; kk < 4; ++kk)
            af[mi][kk] = *reinterpret_cast<const bf16x8*>(
                xbf + (((size_t)(n * T + i0 + wave * 32 + mi * 16 + l16)) << 7)
                    + kk * 32 + quad * 8);
    float x2v[8];
    #pragma unroll
    for (int mi = 0; mi < 2; ++mi)
        #pragma unroll
        for (int r = 0; r < 4; ++r)
            x2v[mi * 4 + r] = x2g[n * T + i0 + wave * 32 + mi * 16 + quad * 4 + r];
    #pragma unroll
    for (int e = tid; e < 512; e += 256) y2_sm[e] = y2g[n * T + j0 + e];

    float rmin[8];
    #pragma unroll
    for (int q = 0; q < 8; ++q) rmin[q] = FINF;

    __syncthreads();    // y2_sm visible; tile-0 DMA drained

    for (int jt = 0; jt < 8; ++jt) {
        const int p = jt & 1;
        if (jt < 7) ISSUE_GLLS(p ^ 1, jt + 1);   // overlaps this iter's compute

        float y2v[4];
        #pragma unroll
        for (int ni = 0; ni < 4; ++ni)
            y2v[ni] = y2_sm[jt * 64 + ni * 16 + l16];

        f32x4 acc[2][4];
        #pragma unroll
        for (int mi = 0; mi < 2; ++mi)
            #pragma unroll
            for (int ni = 0; ni < 4; ++ni) {
                f32x4 z = {0.f, 0.f, 0.f, 0.f};
                acc[mi][ni] = z;
            }

        #pragma unroll
        for (int kk = 0; kk < 4; ++kk) {
            bf16x8 bv[4];
            #pragma unroll
            for (int ni = 0; ni < 4; ++ni) {
                int row = ni * 16 + l16;
                int c   = (kk * 4 + quad) ^ (row & 7);
                bv[ni] = *reinterpret_cast<const bf16x8*>(&b_sm[p][(row * 16 + c) * 8]);
            }
            #pragma unroll
            for (int mi = 0; mi < 2; ++mi)
                #pragma unroll
                for (int ni = 0; ni < 4; ++ni)
                    acc[mi][ni] = __builtin_amdgcn_mfma_f32_16x16x32_bf16(
                        af[mi][kk], bv[ni], acc[mi][ni], 0, 0, 0);
        }

        // ---- epilogue: fold mins (norm-add + clamp deferred) ----
        float vcol[4] = {FINF, FINF, FINF, FINF};
        #pragma unroll
        for (int mi = 0; mi < 2; ++mi)
            #pragma unroll
            for (int r = 0; r < 4; ++r) {
                float x2r = x2v[mi * 4 + r];
                #pragma unroll
                for (int ni = 0; ni < 4; ++ni) {
                    float xy = acc[mi][ni][r];
                    rmin[mi * 4 + r] = fminf(rmin[mi * 4 + r], fmaf(-2.f, xy, y2v[ni]));
                    vcol[ni]         = fminf(vcol[ni],         fmaf(-2.f, xy, x2r));
                }
            }
        #pragma unroll
        for (int ni = 0; ni < 4; ++ni) {
            float v = vcol[ni];
            v = fminf(v, __shfl_xor(v, 16));
            v = fminf(v, __shfl_xor(v, 32));
            if (lane < 16)
                atomicMin(&col_min_sm[jt * 64 + ni * 16 + lane], fenc(v));
        }
        __syncthreads();   // drains next-tile DMA; orders buffer reuse
    }

    // ---- flush ----
    #pragma unroll
    for (int mi = 0; mi < 2; ++mi)
        #pragma unroll
        for (int r = 0; r < 4; ++r) {
            float v = rmin[mi * 4 + r];
            v = fminf(v, __shfl_xor(v, 1));
            v = fminf(v, __shfl_xor(v, 2));
            v = fminf(v, __shfl_xor(v, 4));
            v = fminf(v, __shfl_xor(v, 8));
            if (l16 == 0)
                atomicMin(&g_rowmin[n * T + i0 + wave * 32 + mi * 16 + quad * 4 + r], fenc(v));
        }
    #pragma unroll
    for (int e = tid; e < 512; e += 256)
        atomicMin(&g_colmin[n * T + j0 + e], col_min_sm[e]);
}

// Phase 2: sum sqrt(min d^2) per direction; last block finalizes (counter trick).
__global__ void wmd_reduce(const unsigned* __restrict__ g_colmin,
                           const unsigned* __restrict__ g_rowmin,
                           const float* __restrict__ x2g,
                           const float* __restrict__ y2g,
                           float* __restrict__ sums,
                           unsigned* __restrict__ counter,
                           float* __restrict__ out) {
    int n = blockIdx.x, t = threadIdx.x;
    float sc = 0.f, sr = 0.f;
    for (int e = t; e < T; e += 256) {
        float cv = fdec(g_colmin[n * T + e]) + y2g[n * T + e];
        float rv = fdec(g_rowmin[n * T + e]) + x2g[n * T + e];
        sc += sqrtf(fmaxf(cv, 0.f));
        sr += sqrtf(fmaxf(rv, 0.f));
    }
    #pragma unroll
    for (int o = 1; o < 64; o <<= 1) {
        sc += __shfl_xor(sc, o);
        sr += __shfl_xor(sr, o);
    }
    __shared__ float bc[4], br[4];
    int lane = t & 63, wv = t >> 6;
    if (lane == 0) { bc[wv] = sc; br[wv] = sr; }
    __syncthreads();
    if (t == 0) {
        atomicAdd(&sums[0], bc[0] + bc[1] + bc[2] + bc[3]);
        atomicAdd(&sums[1], br[0] + br[1] + br[2] + br[3]);
        __threadfence();
        unsigned old = atomicAdd(counter, 1u);
        if (old == NB - 1) {
            float a = atomicAdd(&sums[0], 0.f);   // coherent reads
            float b = atomicAdd(&sums[1], 0.f);
            out[0] = fmaxf(a, b) * (1.0f / 67108864.0f);
        }
    }
}

extern "C" void kernel_launch(void* const* d_in, const int* in_sizes, int n_in,
                              void* d_out, int out_size, void* d_ws, size_t ws_size,
                              hipStream_t stream) {
    const float* x = (const float*)d_in[0];
    const float* y = (const float*)d_in[1];
    float* out = (float*)d_out;

    char* ws = (char*)d_ws;
    unsigned* g_colmin = (unsigned*)(ws);                    // 256 KB
    unsigned* g_rowmin = (unsigned*)(ws + 256 * 1024);       // 256 KB
    float*    x2g      = (float*)(ws + 512 * 1024);          // 256 KB
    float*    y2g      = (float*)(ws + 768 * 1024);          // 256 KB
    float*    sums     = (float*)(ws + 1024 * 1024);         // 2 f32
    unsigned* counter  = (unsigned*)(ws + 1024 * 1024 + 8);  // 1 u32
    short*    xbf      = (short*)(ws + 2 * 1024 * 1024);     // 16 MB
    short*    ybf      = (short*)(ws + 20 * 1024 * 1024);    // 16 MB

    wmd_prep<<<(NB * T * HD / 4) / 256, 256, 0, stream>>>(
        x, y, xbf, ybf, x2g, y2g, g_colmin, g_rowmin, sums, counter);
    wmd_main<<<dim3(16, NB), 256, 0, stream>>>(xbf, ybf, x2g, y2g, g_colmin, g_rowmin);
    wmd_reduce<<<NB, 256, 0, stream>>>(g_colmin, g_rowmin, x2g, y2g, sums, counter, out);
}